// Round 12
// baseline (221.160 us; speedup 1.0000x reference)
//
#include <hip/hip_runtime.h>

// ---------------------------------------------------------------------------
// self_transformer: q=xW1^T+b1, k=xW2^T+b2, v=xW3^T+b3,
//                   attn=softmax((k q^T)/sqrt(D)), out=attn@v
// N=4096, D=1024. All matmuls via mfma_f32_16x16x32_bf16, fp32 accum.
// R19 = occupancy-2 gemm: tile 128x256, BK=32, 512 threads (8 waves,
//       per-wave 64x64), LDS 48 KiB double-buffered -> 512-block grids =
//       2 blocks/CU (4 waves/SIMD). Mechanism: R8-R18 all ran 1 block/CU
//       where barrier-locked waves alternate LDS-burst <-> MFMA-burst
//       (MfmaUtil pinned at 29% across 7 schedule variants). Independent
//       co-resident blocks run anti-phase: one block's MFMA covers the
//       other's ds_read/stage drain (m114/m97: implicit wave-level overlap
//       at >=2 blocks/CU captures what source pipelining could not).
//       R18's transpose-fold REVERTED (template-codegen contamination:
//       +393K conflicts on every instantiation). R13-R16 fusions REVERTED.
//   Schedule (simple, robust): per K-tile {ldfrags, lgkmcnt(0), BAR,
//   stage(t+2) -> buf just read, 16 MFMA (setprio), WAITV(3) counted
//   (0 only at tail), BAR}. Ledger: tile t staged at iter t-2, retired by
//   iter t-1's WAITV(3) (3 newest outstanding = iter t-1's own stage);
//   WAR: stage targets the buffer whose reads all waves drained before
//   this BAR. Prologue stages tiles 0,1; WAITV(3) retires tile 0 only.
//   LDS [rows][4 granules of 8 shorts], slot = granule ^ ((row>>1)&3):
//   read pattern = 2 lanes/bank (free); gld_lds dests linear per wave.
//   Per-element accumulation order (ascending K=32 chunks) identical to
//   R12 -> bit-identical gemm numerics.
// ---------------------------------------------------------------------------

typedef short bf16x8 __attribute__((ext_vector_type(8)));  // 8 bf16 = 4 VGPRs
typedef float f32x4  __attribute__((ext_vector_type(4)));

__device__ __forceinline__ short f2bf(float f) {
    unsigned u = __builtin_bit_cast(unsigned, f);
    u += 0x7FFFu + ((u >> 16) & 1u);   // round-to-nearest-even
    return (short)(u >> 16);
}
__device__ __forceinline__ float bf2f(short s) {
    return __builtin_bit_cast(float, (unsigned)((unsigned short)s) << 16);
}

__device__ __forceinline__ void gld_lds16(const short* g, short* l) {
    __builtin_amdgcn_global_load_lds(
        (const __attribute__((address_space(1))) void*)g,
        (__attribute__((address_space(3))) void*)l, 16, 0, 0);
}

#define WAITV(n) asm volatile("s_waitcnt vmcnt(" #n ")" ::: "memory")
#define LGKM0()  asm volatile("s_waitcnt lgkmcnt(0)" ::: "memory")
#define BAR()    __builtin_amdgcn_s_barrier()

// ---------------------------------------------------------------------------
// 128x256 BT GEMM, BK=32, 512 threads = 8 waves (2M x 4N), per-wave 64x64.
// C[a][b] = scale * sum_i A[a*lda+i] * B[b*ldb+i].
// CMODE: 0 = bf16 + bias; 2 = bf16 exp(); 3 = bf16 at split-K z*zstride.
// Requires K % 32 == 0, K/32 >= 2.
// ---------------------------------------------------------------------------
template<int CMODE>
__global__ __launch_bounds__(512, 4)   // 4 waves/SIMD -> 2 blocks/CU, VGPR<=128
void gemm128(const short* __restrict__ A, int lda,
             const short* __restrict__ B, int ldb,
             const float* __restrict__ bias,
             short* __restrict__ Cout, int ldc, float scale,
             int K, size_t zstride)
{
    __shared__ __align__(16) short As[2][128 * 32];   // 16 KiB
    __shared__ __align__(16) short Bs[2][256 * 32];   // 32 KiB

    const int tid  = threadIdx.x;
    const int lane = tid & 63;
    const int wave = tid >> 6;           // 0..7
    const int wr   = wave >> 2;          // 0..1  (M strip of 64 rows)
    const int wc   = wave & 3;           // 0..3  (N strip of 64 cols)
    const int quad = lane >> 4;
    const int l16  = lane & 15;
    const size_t bm0 = (size_t)blockIdx.y * 128;
    const size_t bn0 = (size_t)blockIdx.x * 256;
    const int koff = blockIdx.z * K;

    f32x4 acc[4][4] = {};

    // staging decode: a gld_lds covers 16 rows x 32 cols (8 KB/wave-instr).
    // lane l -> row +(l>>2), LDS slot (l&3); fetches global granule
    // (l&3)^((l>>3)&3)  [= slot ^ ((row>>1)&3), row base multiple of 16]
    const int srow  = lane >> 2;
    const int sgran = (lane & 3) ^ ((lane >> 3) & 3);
    const short* Ag = A + (bm0 + wave * 16 + srow) * (size_t)lda + koff + sgran * 8;
    const short* Bg = B + (bn0 + srow) * (size_t)ldb + koff + sgran * 8;

    // fragment reads: row = base + l16, want granule quad ->
    // slot = quad ^ ((row>>1)&3) = quad ^ ((l16>>1)&3)  [bases mult. of 8]
    const int sl   = (l16 >> 1) & 3;
    const int rdA0 = (wr * 64 + l16) * 32;
    const int rdB0 = (wc * 64 + l16) * 32;
    const int soff = ((quad ^ sl) << 3);

    // A: 1 load/thread; B: 2 loads/thread. 3 vmcnt events per stage().
    auto stage = [&](int p, int kt) {
        gld_lds16(Ag + kt, &As[p][wave * 512]);
#pragma unroll
        for (int i = 0; i < 2; ++i)
            gld_lds16(Bg + (size_t)((wave * 2 + i) * 16) * ldb + kt,
                      &Bs[p][(wave * 2 + i) * 512]);
    };

    bf16x8 af[4], bfr[4];
    auto ldfrags = [&](int p) {
#pragma unroll
        for (int n = 0; n < 4; ++n)
            bfr[n] = *(const bf16x8*)(&Bs[p][rdB0 + n * 512 + soff]);
#pragma unroll
        for (int m = 0; m < 4; ++m)
            af[m] = *(const bf16x8*)(&As[p][rdA0 + m * 512 + soff]);
    };
    auto mm = [&]() {
        __builtin_amdgcn_s_setprio(1);
#pragma unroll
        for (int m = 0; m < 4; ++m)
#pragma unroll
            for (int n = 0; n < 4; ++n)
                acc[m][n] = __builtin_amdgcn_mfma_f32_16x16x32_bf16(
                    af[m], bfr[n], acc[m][n], 0, 0, 0);
        __builtin_amdgcn_s_setprio(0);
    };

    const int NT = K >> 5;

    // prologue: tiles 0 and 1; retire tile 0 only (tile 1 stays in flight)
    stage(0, 0);
    stage(1, 32);
    WAITV(3);
    BAR();
    __builtin_amdgcn_sched_barrier(0);

    int p = 0;
    for (int t = 0; t < NT; ++t) {
        ldfrags(p);
        LGKM0();                         // my reads of buf p complete
        BAR();                           // ... across all waves
        if (t + 2 < NT) stage(p, (t + 2) << 5);   // overwrite buf p (WAR-safe)
        mm();
        // retire tile t+1 (in buf p^1): newest 3 loads = this iter's stage
        if (t + 2 < NT) { WAITV(3); } else { WAITV(0); }
        __builtin_amdgcn_sched_barrier(0);
        BAR();
        p ^= 1;
    }

    // epilogue: C/D layout col=lane&15, row=quad*4+reg; store order (m,n,r)
    short* Cs = Cout + ((CMODE == 3) ? (size_t)blockIdx.z * zstride : 0);
#pragma unroll
    for (int m = 0; m < 4; ++m) {
#pragma unroll
        for (int n = 0; n < 4; ++n) {
            const size_t col = bn0 + wc * 64 + n * 16 + l16;
            const float bc = (CMODE == 0) ? bias[col] : 0.0f;
#pragma unroll
            for (int r = 0; r < 4; ++r) {
                const size_t row = bm0 + wr * 64 + m * 16 + quad * 4 + r;
                float v = acc[m][n][r] * scale + bc;
                if (CMODE == 2) v = __expf(v);
                Cs[row * (size_t)ldc + col] = f2bf(v);
            }
        }
    }
}

// 64x64 LDS-tiled transpose: vt[d][n] = qkv[n*3072 + 2048 + d]
__global__ __launch_bounds__(256)
void transpose_v(const short* __restrict__ qkv, short* __restrict__ vt)
{
    __shared__ short sh[64][72];   // +8 pad
    const int n0 = blockIdx.x * 64, d0 = blockIdx.y * 64;
    const int t = threadIdx.x;
    const int r = t >> 2, c = (t & 3) << 4;

    const short* src = qkv + (size_t)(n0 + r) * 3072 + 2048 + d0 + c;
    *(int4*)(&sh[r][c])     = *(const int4*)(src);
    *(int4*)(&sh[r][c + 8]) = *(const int4*)(src + 8);
    __syncthreads();

    short tmp[16];
#pragma unroll
    for (int j = 0; j < 16; j++) tmp[j] = sh[c + j][r];
    short* dst = vt + (size_t)(d0 + r) * 4096 + n0 + c;
    *(int4*)(dst)     = *(const int4*)(tmp);
    *(int4*)(dst + 8) = *(const int4*)(tmp + 8);
}

// One block per output row n: rsum = sum(E[n,:]); out[n,:] =
// (sum_z partial_z[n,:]) / rsum. Partials are bf16, 4 splits of 4096x1024.
__global__ __launch_bounds__(256)
void reduce4div(const short* __restrict__ E, const short* __restrict__ outp,
                float* __restrict__ out)
{
    const int row = blockIdx.x;
    const int t = threadIdx.x;
    const int wave = t >> 6, lane = t & 63;

    // row-sum of E[row][4096], 16 elems/thread
    const short* e = E + (size_t)row * 4096 + (t << 4);
    short sh[16];
    *(int4*)(sh)     = *(const int4*)(e);
    *(int4*)(sh + 8) = *(const int4*)(e + 8);
    float s = 0.0f;
#pragma unroll
    for (int i = 0; i < 16; i++) s += bf2f(sh[i]);
#pragma unroll
    for (int off = 32; off; off >>= 1) s += __shfl_down(s, off);
    __shared__ float red[4];
    if (lane == 0) red[wave] = s;
    __syncthreads();
    const float inv = 1.0f / (red[0] + red[1] + red[2] + red[3]);

    // sum 4 bf16 partial rows, 4 cols/thread
    const size_t base = (size_t)row * 1024 + (t << 2);
    float a[4] = {0.0f, 0.0f, 0.0f, 0.0f};
#pragma unroll
    for (int z = 0; z < 4; z++) {
        short4 p = *(const short4*)(outp + z * (size_t)4096 * 1024 + base);
        a[0] += bf2f(p.x); a[1] += bf2f(p.y);
        a[2] += bf2f(p.z); a[3] += bf2f(p.w);
    }
    float4 o;
    o.x = a[0] * inv; o.y = a[1] * inv; o.z = a[2] * inv; o.w = a[3] * inv;
    *(float4*)(out + base) = o;
}

// single prep: x->xb (1M float4), W1|W2|W3 -> Wb (3x256K float4), bias cat
// Wb sub-matrix offsets are in SHORT ELEMENTS (1048576 elems per W).
__global__ __launch_bounds__(256)
void prep(const float* __restrict__ x, const float* __restrict__ W1,
          const float* __restrict__ W2, const float* __restrict__ W3,
          const float* __restrict__ b1, const float* __restrict__ b2,
          const float* __restrict__ b3,
          short* __restrict__ xb, short* __restrict__ Wb,
          float* __restrict__ bcat)
{
    const int i = blockIdx.x * 256 + threadIdx.x;
    const int NX = 1048576;           // 4096*1024/4
    const int NW = 262144;            // 1024*1024/4
    if (i < NX + 3 * NW) {
        const float* src; short* dst; int j;
        if (i < NX)               { src = x;  dst = xb; j = i; }
        else if (i < NX + NW)     { src = W1; dst = Wb; j = i - NX; }
        else if (i < NX + 2 * NW) { src = W2; dst = Wb + 1048576; j = i - NX - NW; }
        else                      { src = W3; dst = Wb + 2097152; j = i - NX - 2 * NW; }
        const float4 f = ((const float4*)src)[j];
        short4 o;
        o.x = f2bf(f.x); o.y = f2bf(f.y); o.z = f2bf(f.z); o.w = f2bf(f.w);
        *(short4*)(dst + (j << 2)) = o;
    } else {
        const int j = i - (NX + 3 * NW);
        if (j < 3072)
            bcat[j] = (j < 1024) ? b1[j] : (j < 2048 ? b2[j - 1024] : b3[j - 2048]);
    }
}

extern "C" void kernel_launch(void* const* d_in, const int* in_sizes, int n_in,
                              void* d_out, int out_size, void* d_ws, size_t ws_size,
                              hipStream_t stream)
{
    const float* x  = (const float*)d_in[0];
    const float* W1 = (const float*)d_in[1];
    const float* b1 = (const float*)d_in[2];
    const float* W2 = (const float*)d_in[3];
    const float* b2 = (const float*)d_in[4];
    const float* W3 = (const float*)d_in[5];
    const float* b3 = (const float*)d_in[6];
    float* out = (float*)d_out;

    const int N = 4096, D = 1024;

    // workspace (peak 79 MB):
    //   vt   [0, 8M)            live: transpose .. out-gemm
    //   E    [8M, 40M)          live: E-gemm .. reduce
    //   xb   [40M, 48M)  \
    //   Wb   [48M, 54M)   }     dead after E-gemm
    //   bcat [54M, +12K)  }
    //   qkv  [54M+16K, ~78M)   /
    //   outp [40M, 72M)         bf16 partials, overlays dead region
    char* wsb = (char*)d_ws;
    short* vt   = (short*)wsb;                               // 1024x4096 bf16
    short* E    = (short*)(wsb + (size_t)8  * 1024 * 1024);  // 4096x4096 bf16
    short* xb   = (short*)(wsb + (size_t)40 * 1024 * 1024);  // 4096x1024 bf16
    short* Wb   = (short*)(wsb + (size_t)48 * 1024 * 1024);  // 3072x1024 bf16
    float* bcat = (float*)(wsb + (size_t)54 * 1024 * 1024);  // 3072 fp32
    short* qkv  = (short*)(wsb + (size_t)54 * 1024 * 1024 + 16384); // 4096x3072
    short* outp = (short*)(wsb + (size_t)40 * 1024 * 1024);  // 4x 4096x1024 bf16

    // 1) prep: casts + bias concat (one launch)
    prep<<<(1048576 + 3 * 262144 + 3072 + 255) / 256, 256, 0, stream>>>(
        x, W1, W2, W3, b1, b2, b3, xb, Wb, bcat);

    // 2) qkv = x @ [W1;W2;W3]^T + bias  (128x256, grid (12,32)=384)
    dim3 gqkv(3 * D / 256, N / 128);
    gemm128<0><<<gqkv, 512, 0, stream>>>(xb, D, Wb, D, bcat,
                                         qkv, 3 * D, 1.0f, D, 0);

    // 3) vt[d][n] = v[n][d]   grid (64,16)=1024 blocks
    dim3 gt(N / 64, D / 64);
    transpose_v<<<gt, 256, 0, stream>>>(qkv, vt);

    // 4) E = exp((k q^T)/32) bf16  (128x256, grid (16,32)=512 -> 2/CU)
    dim3 gs(N / 256, N / 128);
    gemm128<2><<<gs, 512, 0, stream>>>(qkv + D, 3 * D, qkv, 3 * D,
                                       nullptr, E, N, 0.03125f, D, 0);

    // 5) out partials = E @ vt^T, split-K=4 (grid (4,32,4)=512 -> 2/CU)
    dim3 go(D / 256, N / 128, 4);
    gemm128<3><<<go, 512, 0, stream>>>(E, N, vt, N, nullptr,
                                       outp, D, 1.0f, N / 4,
                                       (size_t)N * D);

    // 6) out = (sum_z partial_z) / rowsum(E)
    reduce4div<<<N, 256, 0, stream>>>(E, outp, out);
}

// Round 13
// 213.264 us; speedup vs baseline: 1.0370x; 1.0370x over previous
//
#include <hip/hip_runtime.h>

// ---------------------------------------------------------------------------
// self_transformer: q=xW1^T+b1, k=xW2^T+b2, v=xW3^T+b3,
//                   attn=softmax((k q^T)/sqrt(D)), out=attn@v
// N=4096, D=1024. All matmuls via mfma_f32_16x16x32_bf16, fp32 accum.
// R20 = exact revert to R12 (best measured: 212.5us). Session ledger:
//   R13 read-ahead+rsum: -5.4us regression; R14 32x32x16 MFMA: 3.1M bank
//   conflicts; R15/R16 rsum fusion: net-negative via write-pattern side
//   effects; R17 cooperative mega-fusion: 317us (I-cache thrash); R18
//   transpose-fold: template codegen contamination (+393K conflicts on
//   every instantiation); R19 occupancy-2: occupancy 17->32% but MfmaUtil
//   unchanged (~30%) -> LDS-read pipe and MFMA pipe are co-equal
//   bottlenecks whose serialization none of 7 schedule variants broke.
//   R12 structure:
//   - 8 phases / 2 K-tiles per iteration; reads issued in consume order
//     (B-ks0, A-ks0, B-ks1, A-ks1); compiler emits per-use counted
//     lgkmcnt; 1 barrier per phase (post-MFMA).
//   - stage rotation ph1:t+1.A1, ph2:t+2.A0, ph3:t+2.B0, ph4:t+2.B1,
//     ph5:t+2.A1, ph6:t+3.A0, ph7:t+3.B0, ph8:t+3.B1; vmcnt(6) publishes
//     at end-ph4 (tile t+1 complete) / end-ph8 (tile t+2 complete), with
//     sched_barrier(0) so no memory op crosses; last iteration peeled
//     (vmcnt(0) only there).
//   WAR safety: every stage targets a slot whose reads completed in an
//   earlier phase. RAW safety: phase-p reads are issued after the publish
//   wait+barrier covering their slot. LDS half [128 rows][8 granules of
//   8 shorts], slot s of row r holds global granule s^(r&7); read slot
//   (ks*4+quad)^(l16&7) -> 0 bank conflicts (measured R7-R13).
//   Epilogue store order (mt,nt,r) — do NOT reorder (R13/R15: +7us).
// ---------------------------------------------------------------------------

typedef short bf16x8 __attribute__((ext_vector_type(8)));  // 8 bf16 = 4 VGPRs
typedef float f32x4  __attribute__((ext_vector_type(4)));

struct FalseT { static constexpr bool value = false; };
struct TrueT  { static constexpr bool value = true;  };

__device__ __forceinline__ short f2bf(float f) {
    unsigned u = __builtin_bit_cast(unsigned, f);
    u += 0x7FFFu + ((u >> 16) & 1u);   // round-to-nearest-even
    return (short)(u >> 16);
}
__device__ __forceinline__ float bf2f(short s) {
    return __builtin_bit_cast(float, (unsigned)((unsigned short)s) << 16);
}

__device__ __forceinline__ void gld_lds16(const short* g, short* l) {
    __builtin_amdgcn_global_load_lds(
        (const __attribute__((address_space(1))) void*)g,
        (__attribute__((address_space(3))) void*)l, 16, 0, 0);
}

#define WAITV(n) asm volatile("s_waitcnt vmcnt(" #n ")" ::: "memory")
#define BAR()    __builtin_amdgcn_s_barrier()

// ---------------------------------------------------------------------------
// 256x256 BT GEMM, BK=64, 512 threads = 8 waves (2M x 4N), per-wave 128x64
// output spread across quadrant halves. C[a][b] = scale * sum A[a,i]*B[b,i].
// CMODE: 0 = bf16 + bias; 2 = bf16 exp(); 3 = bf16 at split-K z*zstride.
// Requires K % 128 == 0.
// ---------------------------------------------------------------------------
template<int CMODE>
__global__ __launch_bounds__(512)
void gemm256(const short* __restrict__ A, int lda,
             const short* __restrict__ B, int ldb,
             const float* __restrict__ bias,
             short* __restrict__ Cout, int ldc, float scale,
             int K, size_t zstride)
{
    __shared__ __align__(16) short As[2][2][128 * 64];  // [parity][mq-half]
    __shared__ __align__(16) short Bs[2][2][128 * 64];  // [parity][nq-half]

    const int tid  = threadIdx.x;
    const int lane = tid & 63;
    const int wave = tid >> 6;           // 0..7
    const int wr   = wave >> 2;          // 0..1
    const int wc   = wave & 3;           // 0..3
    const int quad = lane >> 4;
    const int l16  = lane & 15;
    const size_t bm0 = (size_t)blockIdx.y * 256;
    const size_t bn0 = (size_t)blockIdx.x * 256;
    const int koff = blockIdx.z * K;

    f32x4 acc[8][4] = {};

    // staging decode: stage call writes 16 rows (wave*16..+15) of one half;
    // lane l -> row +8*i+(l>>3), LDS slot (l&7), global granule (l&7)^(l>>3)
    const int srow  = lane >> 3;
    const int sgran = (lane & 7) ^ srow;
    const short* Ag0 = A + (bm0 + wave * 16 + srow) * (size_t)lda + koff + sgran * 8;
    const short* Ag1 = Ag0 + (size_t)128 * lda;
    const short* Bg0 = B + (bn0 + wave * 16 + srow) * (size_t)ldb + koff + sgran * 8;
    const short* Bg1 = Bg0 + (size_t)128 * ldb;

    // fragment read offsets within a [128][64] half
    const int s0   = ((quad ^ (l16 & 7)) << 3);         // ks=0 slot
    const int s1   = (((4 + quad) ^ (l16 & 7)) << 3);   // ks=1 slot
    const int rdA0 = (wr * 64 + l16) * 64;
    const int rdB0 = (wc * 32 + l16) * 64;

    auto stage = [&](short* half, const short* g, int ld, int kt) {
#pragma unroll
        for (int i = 0; i < 2; ++i)
            gld_lds16(g + (size_t)(i * 8) * ld + kt,
                      half + (wave * 16 + i * 8) * 64);
    };

    bf16x8 af[4][2], bfr0[2][2], bfr1[2][2];

    auto ldA = [&](const short* Ah, int ks, int soff) {
#pragma unroll
        for (int m4 = 0; m4 < 4; ++m4)
            af[m4][ks] = *(const bf16x8*)(Ah + rdA0 + m4 * 1024 + soff);
    };
    auto ldB = [&](bf16x8 (&bx)[2][2], const short* Bh, int ks, int soff) {
#pragma unroll
        for (int n2 = 0; n2 < 2; ++n2)
            bx[n2][ks] = *(const bf16x8*)(Bh + rdB0 + n2 * 1024 + soff);
    };
    auto mmks = [&](int mq, int nq, bf16x8 (&bx)[2][2], int ks) {
#pragma unroll
        for (int m4 = 0; m4 < 4; ++m4)
#pragma unroll
            for (int n2 = 0; n2 < 2; ++n2)
                acc[mq * 4 + m4][nq * 2 + n2] =
                    __builtin_amdgcn_mfma_f32_16x16x32_bf16(
                        af[m4][ks], bx[n2][ks],
                        acc[mq * 4 + m4][nq * 2 + n2], 0, 0, 0);
    };

    // prologue: tile0 all 4 halves (8 loads, retired by vmcnt(6)), then
    // tile1 {A0,B0,B1} (6 loads, stay in flight). tile1.A1 staged at ph1.
    stage(&As[0][0][0], Ag0, lda, 0);
    stage(&Bs[0][0][0], Bg0, ldb, 0);
    stage(&Bs[0][1][0], Bg1, ldb, 0);
    stage(&As[0][1][0], Ag1, lda, 0);
    stage(&As[1][0][0], Ag0, lda, 64);
    stage(&Bs[1][0][0], Bg0, ldb, 64);
    stage(&Bs[1][1][0], Bg1, ldb, 64);
    WAITV(6);
    BAR();
    __builtin_amdgcn_sched_barrier(0);

    int kt = 0;
    auto iterbody = [&](auto LASTC) {
        constexpr bool LAST = decltype(LASTC)::value;
        // ---- ph1: tile t, quadrant (0,0) ----
        ldB(bfr0, &Bs[0][0][0], 0, s0);
        ldA(&As[0][0][0], 0, s0);
        ldB(bfr0, &Bs[0][0][0], 1, s1);
        ldA(&As[0][0][0], 1, s1);
        stage(&As[1][1][0], Ag1, lda, kt + 64);        // t+1.A1
        __builtin_amdgcn_s_setprio(1);
        mmks(0, 0, bfr0, 0); mmks(0, 0, bfr0, 1);
        __builtin_amdgcn_s_setprio(0);
        BAR();
        // ---- ph2: (0,1) ----
        ldB(bfr1, &Bs[0][1][0], 0, s0);
        ldB(bfr1, &Bs[0][1][0], 1, s1);
        if constexpr (!LAST) stage(&As[0][0][0], Ag0, lda, kt + 128);  // t+2.A0
        __builtin_amdgcn_s_setprio(1);
        mmks(0, 1, bfr1, 0); mmks(0, 1, bfr1, 1);
        __builtin_amdgcn_s_setprio(0);
        BAR();
        // ---- ph3: (1,1) ----
        ldA(&As[0][1][0], 0, s0);
        ldA(&As[0][1][0], 1, s1);
        if constexpr (!LAST) stage(&Bs[0][0][0], Bg0, ldb, kt + 128);  // t+2.B0
        __builtin_amdgcn_s_setprio(1);
        mmks(1, 1, bfr1, 0); mmks(1, 1, bfr1, 1);
        __builtin_amdgcn_s_setprio(0);
        BAR();
        // ---- ph4: (1,0) — register-only MFMA, publish tile t+1 ----
        if constexpr (!LAST) stage(&Bs[0][1][0], Bg1, ldb, kt + 128);  // t+2.B1
        __builtin_amdgcn_s_setprio(1);
        mmks(1, 0, bfr0, 0); mmks(1, 0, bfr0, 1);
        __builtin_amdgcn_s_setprio(0);
        if constexpr (LAST) { WAITV(0); } else { WAITV(6); }
        __builtin_amdgcn_sched_barrier(0);
        BAR();
        // ---- ph5: tile t+1, quadrant (0,0) ----
        ldB(bfr0, &Bs[1][0][0], 0, s0);
        ldA(&As[1][0][0], 0, s0);
        ldB(bfr0, &Bs[1][0][0], 1, s1);
        ldA(&As[1][0][0], 1, s1);
        if constexpr (!LAST) stage(&As[0][1][0], Ag1, lda, kt + 128);  // t+2.A1
        __builtin_amdgcn_s_setprio(1);
        mmks(0, 0, bfr0, 0); mmks(0, 0, bfr0, 1);
        __builtin_amdgcn_s_setprio(0);
        BAR();
        // ---- ph6: (0,1) ----
        ldB(bfr1, &Bs[1][1][0], 0, s0);
        ldB(bfr1, &Bs[1][1][0], 1, s1);
        if constexpr (!LAST) stage(&As[1][0][0], Ag0, lda, kt + 192);  // t+3.A0
        __builtin_amdgcn_s_setprio(1);
        mmks(0, 1, bfr1, 0); mmks(0, 1, bfr1, 1);
        __builtin_amdgcn_s_setprio(0);
        BAR();
        // ---- ph7: (1,1) ----
        ldA(&As[1][1][0], 0, s0);
        ldA(&As[1][1][0], 1, s1);
        if constexpr (!LAST) stage(&Bs[1][0][0], Bg0, ldb, kt + 192);  // t+3.B0
        __builtin_amdgcn_s_setprio(1);
        mmks(1, 1, bfr1, 0); mmks(1, 1, bfr1, 1);
        __builtin_amdgcn_s_setprio(0);
        BAR();
        // ---- ph8: (1,0) — register-only MFMA, publish tile t+2 ----
        if constexpr (!LAST) stage(&Bs[1][1][0], Bg1, ldb, kt + 192);  // t+3.B1
        __builtin_amdgcn_s_setprio(1);
        mmks(1, 0, bfr0, 0); mmks(1, 0, bfr0, 1);
        __builtin_amdgcn_s_setprio(0);
        if constexpr (!LAST) {
            WAITV(6);
            __builtin_amdgcn_sched_barrier(0);
        }
        BAR();
    };

    const int nfull = (K >> 7) - 1;      // K % 128 == 0
    for (int i = 0; i < nfull; ++i) {
        iterbody(FalseT{});
        kt += 128;
    }
    iterbody(TrueT{});

    // epilogue: C/D layout col=lane&15, row=quad*4+reg; wave rows/cols are
    // split across the two quadrant halves.
    short* Cs = Cout + ((CMODE == 3) ? (size_t)blockIdx.z * zstride : 0);
#pragma unroll
    for (int mt = 0; mt < 8; ++mt) {
        const int mq = mt >> 2, m4 = mt & 3;
#pragma unroll
        for (int nt = 0; nt < 4; ++nt) {
            const int nq = nt >> 1, n2 = nt & 1;
            const size_t col = bn0 + nq * 128 + wc * 32 + n2 * 16 + l16;
            const float bc = (CMODE == 0) ? bias[col] : 0.0f;
#pragma unroll
            for (int r = 0; r < 4; ++r) {
                const size_t row = bm0 + mq * 128 + wr * 64 + m4 * 16 + quad * 4 + r;
                float v = acc[mt][nt][r] * scale + bc;
                if (CMODE == 2) v = __expf(v);
                Cs[row * (size_t)ldc + col] = f2bf(v);
            }
        }
    }
}

// 64x64 LDS-tiled transpose: vt[d][n] = qkv[n*3072 + 2048 + d]
__global__ __launch_bounds__(256)
void transpose_v(const short* __restrict__ qkv, short* __restrict__ vt)
{
    __shared__ short sh[64][72];   // +8 pad
    const int n0 = blockIdx.x * 64, d0 = blockIdx.y * 64;
    const int t = threadIdx.x;
    const int r = t >> 2, c = (t & 3) << 4;

    const short* src = qkv + (size_t)(n0 + r) * 3072 + 2048 + d0 + c;
    *(int4*)(&sh[r][c])     = *(const int4*)(src);
    *(int4*)(&sh[r][c + 8]) = *(const int4*)(src + 8);
    __syncthreads();

    short tmp[16];
#pragma unroll
    for (int j = 0; j < 16; j++) tmp[j] = sh[c + j][r];
    short* dst = vt + (size_t)(d0 + r) * 4096 + n0 + c;
    *(int4*)(dst)     = *(const int4*)(tmp);
    *(int4*)(dst + 8) = *(const int4*)(tmp + 8);
}

// One block per output row n: rsum = sum(E[n,:]); out[n,:] =
// (sum_z partial_z[n,:]) / rsum. Partials are bf16, 4 splits of 4096x1024.
__global__ __launch_bounds__(256)
void reduce4div(const short* __restrict__ E, const short* __restrict__ outp,
                float* __restrict__ out)
{
    const int row = blockIdx.x;
    const int t = threadIdx.x;
    const int wave = t >> 6, lane = t & 63;

    // row-sum of E[row][4096], 16 elems/thread
    const short* e = E + (size_t)row * 4096 + (t << 4);
    short sh[16];
    *(int4*)(sh)     = *(const int4*)(e);
    *(int4*)(sh + 8) = *(const int4*)(e + 8);
    float s = 0.0f;
#pragma unroll
    for (int i = 0; i < 16; i++) s += bf2f(sh[i]);
#pragma unroll
    for (int off = 32; off; off >>= 1) s += __shfl_down(s, off);
    __shared__ float red[4];
    if (lane == 0) red[wave] = s;
    __syncthreads();
    const float inv = 1.0f / (red[0] + red[1] + red[2] + red[3]);

    // sum 4 bf16 partial rows, 4 cols/thread
    const size_t base = (size_t)row * 1024 + (t << 2);
    float a[4] = {0.0f, 0.0f, 0.0f, 0.0f};
#pragma unroll
    for (int z = 0; z < 4; z++) {
        short4 p = *(const short4*)(outp + z * (size_t)4096 * 1024 + base);
        a[0] += bf2f(p.x); a[1] += bf2f(p.y);
        a[2] += bf2f(p.z); a[3] += bf2f(p.w);
    }
    float4 o;
    o.x = a[0] * inv; o.y = a[1] * inv; o.z = a[2] * inv; o.w = a[3] * inv;
    *(float4*)(out + base) = o;
}

// single prep: x->xb (1M float4), W1|W2|W3 -> Wb (3x256K float4), bias cat
// Wb sub-matrix offsets are in SHORT ELEMENTS (1048576 elems per W).
__global__ __launch_bounds__(256)
void prep(const float* __restrict__ x, const float* __restrict__ W1,
          const float* __restrict__ W2, const float* __restrict__ W3,
          const float* __restrict__ b1, const float* __restrict__ b2,
          const float* __restrict__ b3,
          short* __restrict__ xb, short* __restrict__ Wb,
          float* __restrict__ bcat)
{
    const int i = blockIdx.x * 256 + threadIdx.x;
    const int NX = 1048576;           // 4096*1024/4
    const int NW = 262144;            // 1024*1024/4
    if (i < NX + 3 * NW) {
        const float* src; short* dst; int j;
        if (i < NX)               { src = x;  dst = xb; j = i; }
        else if (i < NX + NW)     { src = W1; dst = Wb; j = i - NX; }
        else if (i < NX + 2 * NW) { src = W2; dst = Wb + 1048576; j = i - NX - NW; }
        else                      { src = W3; dst = Wb + 2097152; j = i - NX - 2 * NW; }
        const float4 f = ((const float4*)src)[j];
        short4 o;
        o.x = f2bf(f.x); o.y = f2bf(f.y); o.z = f2bf(f.z); o.w = f2bf(f.w);
        *(short4*)(dst + (j << 2)) = o;
    } else {
        const int j = i - (NX + 3 * NW);
        if (j < 3072)
            bcat[j] = (j < 1024) ? b1[j] : (j < 2048 ? b2[j - 1024] : b3[j - 2048]);
    }
}

extern "C" void kernel_launch(void* const* d_in, const int* in_sizes, int n_in,
                              void* d_out, int out_size, void* d_ws, size_t ws_size,
                              hipStream_t stream)
{
    const float* x  = (const float*)d_in[0];
    const float* W1 = (const float*)d_in[1];
    const float* b1 = (const float*)d_in[2];
    const float* W2 = (const float*)d_in[3];
    const float* b2 = (const float*)d_in[4];
    const float* W3 = (const float*)d_in[5];
    const float* b3 = (const float*)d_in[6];
    float* out = (float*)d_out;

    const int N = 4096, D = 1024;

    // workspace (peak 79 MB):
    //   vt   [0, 8M)            live: transpose .. out-gemm
    //   E    [8M, 40M)          live: S-gemm .. reduce
    //   xb   [40M, 48M)  \
    //   Wb   [48M, 54M)   }     dead after S-gemm
    //   bcat [54M, +12K)  }
    //   qkv  [54M+16K, ~78M)   /
    //   outp [40M, 72M)         bf16 partials, overlays dead region
    char* wsb = (char*)d_ws;
    short* vt   = (short*)wsb;                               // 1024x4096 bf16
    short* E    = (short*)(wsb + (size_t)8  * 1024 * 1024);  // 4096x4096 bf16
    short* xb   = (short*)(wsb + (size_t)40 * 1024 * 1024);  // 4096x1024 bf16
    short* Wb   = (short*)(wsb + (size_t)48 * 1024 * 1024);  // 3072x1024 bf16
    float* bcat = (float*)(wsb + (size_t)54 * 1024 * 1024);  // 3072 fp32
    short* qkv  = (short*)(wsb + (size_t)54 * 1024 * 1024 + 16384); // 4096x3072
    short* outp = (short*)(wsb + (size_t)40 * 1024 * 1024);  // 4x 4096x1024 bf16

    // 1) prep: casts + bias concat (one launch)
    prep<<<(1048576 + 3 * 262144 + 3072 + 255) / 256, 256, 0, stream>>>(
        x, W1, W2, W3, b1, b2, b3, xb, Wb, bcat);

    // 2) qkv = x @ [W1;W2;W3]^T + bias  (256x256, grid (12,16)=192)
    dim3 gqkv(3 * D / 256, N / 256);
    gemm256<0><<<gqkv, 512, 0, stream>>>(xb, D, Wb, D, bcat,
                                         qkv, 3 * D, 1.0f, D, 0);

    // 3) vt[d][n] = v[n][d]   grid (64,16)=1024 blocks
    dim3 gt(N / 64, D / 64);
    transpose_v<<<gt, 256, 0, stream>>>(qkv, vt);

    // 4) E = exp((k q^T)/32) bf16  (256x256, grid (16,16)=256)
    dim3 gs(N / 256, N / 256);
    gemm256<2><<<gs, 512, 0, stream>>>(qkv + D, 3 * D, qkv, 3 * D,
                                       nullptr, E, N, 0.03125f, D, 0);

    // 5) out partials = E @ vt^T, split-K=4, bf16 (grid (4,16,4)=256)
    dim3 go(D / 256, N / 256, 4);
    gemm256<3><<<go, 512, 0, stream>>>(E, N, vt, N, nullptr,
                                       outp, D, 1.0f, N / 4,
                                       (size_t)N * D);

    // 6) out = (sum_z partial_z) / rowsum(E)
    reduce4div<<<N, 256, 0, stream>>>(E, outp, out);
}